// Round 4
// baseline (749.060 us; speedup 1.0000x reference)
//
#include <hip/hip_runtime.h>
#include <hip/hip_bf16.h>
#include <math.h>

#define BATCH 512
#define DIM 512
#define NCLASS 100000
#define BNB 256                      /* block tile cols */
#define NT 391                       /* ceil(100000/256) */
#define NSTREAM 64
#define GRID 512                     /* 8 M-groups x 64 streams = 2 blocks/CU */
#define S_SCALE 30.0f
#define COSM 0.8775825618903728f
#define SINM 0.4794255386042030f
#define LOG2E 1.44269504088896f

typedef unsigned short u16;
typedef __attribute__((ext_vector_type(8))) short short8;
typedef __attribute__((ext_vector_type(4))) float floatx4;
typedef __attribute__((ext_vector_type(16))) float floatx16;

// ws layout (bytes):
//   [0, 524288)         xn bf16 [512][512]  (written by stream-0 blocks, read by reduce_lse)
//   [524288, 655360)    partials [64 streams][512 rows] f32
//   [655360, 657408)    nll float[512]

__device__ __forceinline__ u16 f2bf(float f) {
    union { __hip_bfloat16 h; u16 u; } c;
    c.h = __float2bfloat16(f);       // RNE, native v_cvt on gfx950
    return c.u;
}
__device__ __forceinline__ float bf2f(u16 b) {
    union { float f; unsigned int u; } v;
    v.u = ((unsigned int)b) << 16;
    return v.f;
}

// convert 8 fp32 -> short8 of bf16 (RNE)
__device__ __forceinline__ short8 cvt_bf8(floatx4 a, floatx4 b) {
    union { short8 s8; u16 u[8]; } p;
#pragma unroll
    for (int j = 0; j < 4; ++j) p.u[j] = f2bf(a[j]);
#pragma unroll
    for (int j = 0; j < 4; ++j) p.u[4 + j] = f2bf(b[j]);
    return p.s8;
}

// ---------------- Kernel 1: A-stationary streaming GEMM (xnorm fused) ----------------
// 512 blocks = 8 M-groups (64 rows) x 64 tile-streams; 2 blocks/CU, 16 waves/CU.
// A slice (64x512 bf16, normalized in prologue) pinned in swizzled LDS.
// W fp32 streamed global->reg->bf16->MFMA (depth-3 register pipeline), no
// barriers in the main loop, running exp-sums kept in registers.
// MFMA 32x32x16: A row=lane&31, k=(lane>>5)*8+j; C/D col=lane&31,
// row=(reg&3)+8*(reg>>2)+4*(lane>>5)   [m74/m101-verified; round-3 correct].
__global__ __launch_bounds__(512, 4) void arcface_main(
        const float* __restrict__ x, const float* __restrict__ w,
        u16* __restrict__ xn, float* __restrict__ partials) {
    __shared__ __align__(16) u16 ash[64 * DIM];    // 64 KB swizzled normalized-A
    __shared__ float pacc[8][64];                  // cross-wave row-sum buffer

    const int t = threadIdx.x;
    const int bid = blockIdx.x;
    const int stream = bid & 63;
    const int mgrp = bid >> 6;       // 0..7
    const int wv = t >> 6;           // 0..7 = col slot (32 cols each)
    const int lane = t & 63;
    const int l31 = lane & 31;
    const int hi = lane >> 5;

    // ---- prologue: normalize this block's 64 x-rows -> bf16, swizzled LDS ----
    {
        const int r = t >> 3;        // local row 0..63
        const int q = t & 7;         // 8 threads per row
        const float* xr = x + (size_t)(mgrp * 64 + r) * DIM;
        floatx4 v[16];
        float ss = 0.f;
#pragma unroll
        for (int i = 0; i < 16; ++i) {
            v[i] = *(const floatx4*)(xr + ((q + (i << 3)) << 2));
            ss += v[i][0]*v[i][0] + v[i][1]*v[i][1] + v[i][2]*v[i][2] + v[i][3]*v[i][3];
        }
        ss += __shfl_xor(ss, 1);
        ss += __shfl_xor(ss, 2);
        ss += __shfl_xor(ss, 4);
        const float rn = 1.0f / fmaxf(sqrtf(ss), 1e-12f);
#pragma unroll
        for (int i = 0; i < 16; ++i) {
            const int col4 = q + (i << 3);
            const int gp = (col4 >> 1) ^ (r & 7);        // swizzled 16B granule
            ushort4 u;
            u.x = f2bf(v[i][0]*rn); u.y = f2bf(v[i][1]*rn);
            u.z = f2bf(v[i][2]*rn); u.w = f2bf(v[i][3]*rn);
            *(ushort4*)(&ash[r * DIM + gp * 8 + (col4 & 1) * 4]) = u;
            if (stream == 0)   // publish exact bf16 x-hat once for reduce_lse
                *(ushort4*)(xn + (size_t)(mgrp * 64 + r) * DIM + col4 * 4) = u;
        }
    }
    __syncthreads();

    float run0[16], run1[16];
#pragma unroll
    for (int r = 0; r < 16; ++r) { run0[r] = 0.f; run1[r] = 0.f; }

    const int aoff0 = l31 * DIM;          // rows 0..31
    const int aoff1 = (32 + l31) * DIM;   // rows 32..63

    for (int tile = stream; tile < NT; tile += NSTREAM) {
        const int c0 = tile * BNB + wv * 32;
        const bool vfrag = c0 < NCLASS;          // NCLASS%32==0: frags never partial
        const int cc = min(c0 + l31, NCLASS - 1);
        const float* wp = w + (size_t)cc * DIM + hi * 8;

        floatx4 pb[3][2];                        // depth-3 in-flight W fp32
#pragma unroll
        for (int p = 0; p < 3; ++p) {
            pb[p][0] = *(const floatx4*)(wp + (p << 4));
            pb[p][1] = *(const floatx4*)(wp + (p << 4) + 4);
        }

        floatx16 acc0 = (floatx16)0.0f, acc1 = (floatx16)0.0f;
        float ssq = 0.f;

#pragma unroll
        for (int ks = 0; ks < 32; ++ks) {
            const int sl = ks % 3;               // compile-time (unrolled)
            const floatx4 lo = pb[sl][0], hp = pb[sl][1];
            ssq += lo[0]*lo[0] + lo[1]*lo[1] + lo[2]*lo[2] + lo[3]*lo[3]
                 + hp[0]*hp[0] + hp[1]*hp[1] + hp[2]*hp[2] + hp[3]*hp[3];
            const short8 bfr = cvt_bf8(lo, hp);
            if (ks < 29) {
                pb[sl][0] = *(const floatx4*)(wp + ((ks + 3) << 4));
                pb[sl][1] = *(const floatx4*)(wp + ((ks + 3) << 4) + 4);
            }
            const int gb = (((ks << 1) + hi) ^ (l31 & 7)) << 3;  // u16 offset in row
            const short8 a0 = *(const short8*)(&ash[aoff0 + gb]);
            const short8 a1 = *(const short8*)(&ash[aoff1 + gb]);
            acc0 = __builtin_amdgcn_mfma_f32_32x32x16_bf16(a0, bfr, acc0, 0, 0, 0);
            acc1 = __builtin_amdgcn_mfma_f32_32x32x16_bf16(a1, bfr, acc1, 0, 0, 0);
        }

        ssq += __shfl_xor(ssq, 32);              // join the two k-halves
        if (vfrag) {
            const float sa = S_SCALE * (1.0f / fmaxf(sqrtf(ssq), 1e-12f)) * LOG2E;
            const float sb = -S_SCALE * LOG2E;
#pragma unroll
            for (int r = 0; r < 16; ++r) {
                run0[r] += exp2f(fmaf(acc0[r], sa, sb));
                run1[r] += exp2f(fmaf(acc1[r], sa, sb));
            }
        }
    }

    // ---- cross-wave row reduction, single partials write ----
#pragma unroll
    for (int r = 0; r < 16; ++r) {
        float s0 = run0[r], s1 = run1[r];
        s0 += __shfl_xor(s0, 1);  s1 += __shfl_xor(s1, 1);
        s0 += __shfl_xor(s0, 2);  s1 += __shfl_xor(s1, 2);
        s0 += __shfl_xor(s0, 4);  s1 += __shfl_xor(s1, 4);
        s0 += __shfl_xor(s0, 8);  s1 += __shfl_xor(s1, 8);
        s0 += __shfl_xor(s0, 16); s1 += __shfl_xor(s1, 16);
        if (l31 == 0) {
            const int row32 = (r & 3) + ((r >> 2) << 3) + (hi << 2);
            pacc[wv][row32]      = s0;
            pacc[wv][32 + row32] = s1;
        }
    }
    __syncthreads();
    if (t < 64) {
        float s = 0.f;
#pragma unroll
        for (int v = 0; v < 8; ++v) s += pacc[v][t];
        partials[(size_t)stream * BATCH + mgrp * 64 + t] = s;
    }
}

// ---------------- Kernel 2: LSE + exact target term + nll ----------------
__global__ void reduce_lse(const float* __restrict__ partials,
                           const float* __restrict__ w,
                           const u16* __restrict__ xn,
                           const int* __restrict__ target,
                           float* __restrict__ nll) {
    const int m = blockIdx.x;
    const int t = threadIdx.x; // 64 = 1 wave
    float tot = partials[(size_t)t * BATCH + m];
#pragma unroll
    for (int d = 1; d < 64; d <<= 1) tot += __shfl_xor(tot, d);

    const int tg = target[m];
    const float* wr = w + (size_t)tg * DIM + t * 8;
    floatx4 w0 = *(const floatx4*)(wr);
    floatx4 w1 = *(const floatx4*)(wr + 4);
    short8 xv = *(const short8*)(xn + (size_t)m * DIM + t * 8);
    float dot = 0.f, ssq = 0.f;
#pragma unroll
    for (int j = 0; j < 4; ++j) {
        ssq += w0[j] * w0[j];
        dot += bf2f((u16)xv[j]) * bf2f(f2bf(w0[j]));   // same bf16 values as MFMA path
    }
#pragma unroll
    for (int j = 0; j < 4; ++j) {
        ssq += w1[j] * w1[j];
        dot += bf2f((u16)xv[4 + j]) * bf2f(f2bf(w1[j]));
    }
#pragma unroll
    for (int d = 1; d < 64; d <<= 1) {
        dot += __shfl_xor(dot, d);
        ssq += __shfl_xor(ssq, d);
    }
    if (t == 0) {
        const float rs = 1.0f / fmaxf(sqrtf(ssq), 1e-12f);
        const float cosv = dot * rs;
        const float sine = sqrtf(fmaxf(1.f - cosv * cosv, 0.f));
        float phi = cosv * COSM - sine * SINM;
        if (!(cosv > 0.f)) phi = cosv;                 // easy_margin
        const float lgp = S_SCALE * phi, lgc = S_SCALE * cosv;
        // main loop summed the target col as a plain class: swap it for phi
        const float tt = tot - __expf(lgc - S_SCALE) + __expf(lgp - S_SCALE);
        nll[m] = (logf(fmaxf(tt, 1e-30f)) + S_SCALE) - lgp;
    }
}

// ---------------- Kernel 3: mean ----------------
__global__ void reduce_mean(const float* __restrict__ nll, float* __restrict__ out) {
    const int t = threadIdx.x; // 512
    float s = nll[t];
#pragma unroll
    for (int d = 1; d < 64; d <<= 1) s += __shfl_xor(s, d);
    __shared__ float red[8];
    if ((t & 63) == 0) red[t >> 6] = s;
    __syncthreads();
    if (t == 0) {
        float tot = 0.f;
#pragma unroll
        for (int i = 0; i < 8; ++i) tot += red[i];
        out[0] = tot / (float)BATCH;
    }
}

extern "C" void kernel_launch(void* const* d_in, const int* in_sizes, int n_in,
                              void* d_out, int out_size, void* d_ws, size_t ws_size,
                              hipStream_t stream) {
    const float* x = (const float*)d_in[0];
    const float* w = (const float*)d_in[1];
    const int* target = (const int*)d_in[2];

    char* ws = (char*)d_ws;
    u16* xn        = (u16*)ws;
    float* partials= (float*)(ws + 524288);
    float* nll     = (float*)(ws + 655360);

    arcface_main<<<GRID, 512, 0, stream>>>(x, w, xn, partials);
    reduce_lse<<<BATCH, 64, 0, stream>>>(partials, w, xn, target, nll);
    reduce_mean<<<1, 512, 0, stream>>>(nll, (float*)d_out);
}

// Round 5
// 727.232 us; speedup vs baseline: 1.0300x; 1.0300x over previous
//
#include <hip/hip_runtime.h>
#include <hip/hip_bf16.h>
#include <math.h>

#define BATCH 512
#define DIM 512
#define NCLASS 100000
#define BNB 256                      /* block tile cols */
#define NT 391                       /* ceil(100000/256) */
#define NSTREAM 64
#define GRID 256                     /* 4 M-groups x 64 streams = 1 block/CU */
#define S_SCALE 30.0f
#define COSM 0.8775825618903728f
#define SINM 0.4794255386042030f
#define LOG2E 1.44269504088896f

typedef unsigned short u16;
typedef __attribute__((ext_vector_type(8))) short short8;
typedef __attribute__((ext_vector_type(4))) float floatx4;
typedef __attribute__((ext_vector_type(16))) float floatx16;

// ws layout (bytes):
//   [0, 524288)         xn bf16 [512][512]  (published by stream-0 blocks)
//   [524288, 655360)    partials [64 streams][512 rows] f32
//   [655360, 657408)    nll float[512]

__device__ __forceinline__ u16 f2bf(float f) {
    union { __hip_bfloat16 h; u16 u; } c;
    c.h = __float2bfloat16(f);       // RNE, native v_cvt on gfx950
    return c.u;
}
__device__ __forceinline__ float bf2f(u16 b) {
    union { float f; unsigned int u; } v;
    v.u = ((unsigned int)b) << 16;
    return v.f;
}

// convert 8 fp32 -> short8 of bf16 (RNE)
__device__ __forceinline__ short8 cvt_bf8(floatx4 a, floatx4 b) {
    union { short8 s8; u16 u[8]; } p;
#pragma unroll
    for (int j = 0; j < 4; ++j) p.u[j] = f2bf(a[j]);
#pragma unroll
    for (int j = 0; j < 4; ++j) p.u[4 + j] = f2bf(b[j]);
    return p.s8;
}

// ---------------- Kernel 1: A-stationary streaming GEMM (xnorm fused) ----------------
// 256 blocks = 4 M-groups (128 rows) x 64 tile-streams; 1 block/CU, 8 waves,
// 2 waves/SIMD -> 256-reg unified budget (no spill: live set ~185).
// A slice (128x512 bf16, normalized in prologue) pinned in swizzled LDS (128 KB).
// W fp32 streamed global->named-reg depth-4 pipeline->bf16->MFMA. No arrays in
// the hot loop (rule #20), no barriers in the main loop, running exp-sums in regs.
// MFMA 32x32x16: A row=lane&31, k=(lane>>5)*8+j; C/D col=lane&31,
// row=(reg&3)+8*(reg>>2)+4*(lane>>5)   [m74/m101-verified; rounds 3-4 correct].
__global__ __launch_bounds__(512, 2) void arcface_main(
        const float* __restrict__ x, const float* __restrict__ w,
        u16* __restrict__ xn, float* __restrict__ partials) {
    __shared__ __align__(16) u16 ash[128 * DIM];   // 128 KB swizzled normalized-A
    __shared__ float pacc[8][128];                 // 4 KB cross-wave row sums

    const int t = threadIdx.x;
    const int bid = blockIdx.x;
    const int stream = bid & 63;
    const int mgrp = bid >> 6;       // 0..3
    const int wv = t >> 6;           // 0..7 = 32-col slot
    const int lane = t & 63;
    const int l31 = lane & 31;
    const int hi = lane >> 5;
    const int swz = l31 & 7;

    // ---- prologue: normalize 128 x-rows -> bf16 swizzled LDS (two 64-row passes) ----
    for (int rp = 0; rp < 2; ++rp) {
        const int r = rp * 64 + (t >> 3);    // local row
        const int q = t & 7;                 // 8 threads per row
        const float* xr = x + (size_t)(mgrp * 128 + r) * DIM;
        floatx4 v[16];
        float ss = 0.f;
#pragma unroll
        for (int i = 0; i < 16; ++i) {
            v[i] = *(const floatx4*)(xr + ((q + (i << 3)) << 2));
            ss += v[i][0]*v[i][0] + v[i][1]*v[i][1] + v[i][2]*v[i][2] + v[i][3]*v[i][3];
        }
        ss += __shfl_xor(ss, 1);
        ss += __shfl_xor(ss, 2);
        ss += __shfl_xor(ss, 4);
        const float rn = 1.0f / fmaxf(sqrtf(ss), 1e-12f);
#pragma unroll
        for (int i = 0; i < 16; ++i) {
            const int col4 = q + (i << 3);
            const int gp = (col4 >> 1) ^ (r & 7);        // swizzled 16B granule
            ushort4 u;
            u.x = f2bf(v[i][0]*rn); u.y = f2bf(v[i][1]*rn);
            u.z = f2bf(v[i][2]*rn); u.w = f2bf(v[i][3]*rn);
            *(ushort4*)(&ash[r * DIM + gp * 8 + (col4 & 1) * 4]) = u;
            if (stream == 0)   // publish exact bf16 x-hat for reduce_lse
                *(ushort4*)(xn + (size_t)(mgrp * 128 + r) * DIM + col4 * 4) = u;
        }
    }
    __syncthreads();

    floatx16 runv0 = (floatx16)0.0f, runv1 = (floatx16)0.0f;
    floatx16 runv2 = (floatx16)0.0f, runv3 = (floatx16)0.0f;

    const int arow0 = l31 * DIM;
    const int arow1 = (32 + l31) * DIM;
    const int arow2 = (64 + l31) * DIM;
    const int arow3 = (96 + l31) * DIM;

    for (int tile = stream; tile < NT; tile += NSTREAM) {
        const int c0 = tile * BNB + wv * 32;
        const bool vfrag = c0 < NCLASS;          // NCLASS%32==0: frags never partial
        const int cc = min(c0 + l31, NCLASS - 1);
        const float* wp = w + (size_t)cc * DIM + hi * 8;

        floatx16 acc0 = (floatx16)0.0f, acc1 = (floatx16)0.0f;
        floatx16 acc2 = (floatx16)0.0f, acc3 = (floatx16)0.0f;
        float ssq = 0.f;

        // depth-4 register pipeline, NAMED slots only (no arrays -> no scratch)
        floatx4 q0a = *(const floatx4*)(wp +  0), q0b = *(const floatx4*)(wp +  4);
        floatx4 q1a = *(const floatx4*)(wp + 16), q1b = *(const floatx4*)(wp + 20);
        floatx4 q2a = *(const floatx4*)(wp + 32), q2b = *(const floatx4*)(wp + 36);
        floatx4 q3a = *(const floatx4*)(wp + 48), q3b = *(const floatx4*)(wp + 52);

        auto step = [&](int kstep, floatx4& qa, floatx4& qb, bool pf) {
            ssq += qa[0]*qa[0] + qa[1]*qa[1] + qa[2]*qa[2] + qa[3]*qa[3]
                 + qb[0]*qb[0] + qb[1]*qb[1] + qb[2]*qb[2] + qb[3]*qb[3];
            const short8 bfr = cvt_bf8(qa, qb);
            if (pf) {
                qa = *(const floatx4*)(wp + ((kstep + 4) << 4));
                qb = *(const floatx4*)(wp + ((kstep + 4) << 4) + 4);
            }
            const int gb = (((kstep << 1) + hi) ^ swz) << 3;   // u16 offset in row
            const short8 a0 = *(const short8*)(&ash[arow0 + gb]);
            const short8 a1 = *(const short8*)(&ash[arow1 + gb]);
            const short8 a2 = *(const short8*)(&ash[arow2 + gb]);
            const short8 a3 = *(const short8*)(&ash[arow3 + gb]);
            acc0 = __builtin_amdgcn_mfma_f32_32x32x16_bf16(a0, bfr, acc0, 0, 0, 0);
            acc1 = __builtin_amdgcn_mfma_f32_32x32x16_bf16(a1, bfr, acc1, 0, 0, 0);
            acc2 = __builtin_amdgcn_mfma_f32_32x32x16_bf16(a2, bfr, acc2, 0, 0, 0);
            acc3 = __builtin_amdgcn_mfma_f32_32x32x16_bf16(a3, bfr, acc3, 0, 0, 0);
        };

        for (int ks = 0; ks < 28; ks += 4) {
            step(ks + 0, q0a, q0b, true);
            step(ks + 1, q1a, q1b, true);
            step(ks + 2, q2a, q2b, true);
            step(ks + 3, q3a, q3b, true);
        }
        step(28, q0a, q0b, false);
        step(29, q1a, q1b, false);
        step(30, q2a, q2b, false);
        step(31, q3a, q3b, false);

        ssq += __shfl_xor(ssq, 32);              // join the two k-halves
        if (vfrag) {
            const float sa = S_SCALE * (1.0f / fmaxf(sqrtf(ssq), 1e-12f)) * LOG2E;
            const float sb = -S_SCALE * LOG2E;
#pragma unroll
            for (int r = 0; r < 16; ++r) {
                runv0[r] += exp2f(fmaf(acc0[r], sa, sb));
                runv1[r] += exp2f(fmaf(acc1[r], sa, sb));
                runv2[r] += exp2f(fmaf(acc2[r], sa, sb));
                runv3[r] += exp2f(fmaf(acc3[r], sa, sb));
            }
        }
    }

    // ---- cross-wave row reduction, single partials write ----
    auto flush = [&](floatx16 rv, int rf) {
#pragma unroll
        for (int r = 0; r < 16; ++r) {
            float s = rv[r];
            s += __shfl_xor(s, 1);
            s += __shfl_xor(s, 2);
            s += __shfl_xor(s, 4);
            s += __shfl_xor(s, 8);
            s += __shfl_xor(s, 16);
            if (l31 == 0)
                pacc[wv][rf * 32 + (r & 3) + ((r >> 2) << 3) + (hi << 2)] = s;
        }
    };
    flush(runv0, 0); flush(runv1, 1); flush(runv2, 2); flush(runv3, 3);
    __syncthreads();
    if (t < 128) {
        float s = 0.f;
#pragma unroll
        for (int v = 0; v < 8; ++v) s += pacc[v][t];
        partials[(size_t)stream * BATCH + mgrp * 128 + t] = s;
    }
}

// ---------------- Kernel 2: LSE + exact target term + nll ----------------
__global__ void reduce_lse(const float* __restrict__ partials,
                           const float* __restrict__ w,
                           const u16* __restrict__ xn,
                           const int* __restrict__ target,
                           float* __restrict__ nll) {
    const int m = blockIdx.x;
    const int t = threadIdx.x; // 64 = 1 wave
    float tot = partials[(size_t)t * BATCH + m];
#pragma unroll
    for (int d = 1; d < 64; d <<= 1) tot += __shfl_xor(tot, d);

    const int tg = target[m];
    const float* wr = w + (size_t)tg * DIM + t * 8;
    floatx4 w0 = *(const floatx4*)(wr);
    floatx4 w1 = *(const floatx4*)(wr + 4);
    short8 xv = *(const short8*)(xn + (size_t)m * DIM + t * 8);
    float dot = 0.f, ssq = 0.f;
#pragma unroll
    for (int j = 0; j < 4; ++j) {
        ssq += w0[j] * w0[j];
        dot += bf2f((u16)xv[j]) * bf2f(f2bf(w0[j]));   // same bf16 values as MFMA path
    }
#pragma unroll
    for (int j = 0; j < 4; ++j) {
        ssq += w1[j] * w1[j];
        dot += bf2f((u16)xv[4 + j]) * bf2f(f2bf(w1[j]));
    }
#pragma unroll
    for (int d = 1; d < 64; d <<= 1) {
        dot += __shfl_xor(dot, d);
        ssq += __shfl_xor(ssq, d);
    }
    if (t == 0) {
        const float rs = 1.0f / fmaxf(sqrtf(ssq), 1e-12f);
        const float cosv = dot * rs;
        const float sine = sqrtf(fmaxf(1.f - cosv * cosv, 0.f));
        float phi = cosv * COSM - sine * SINM;
        if (!(cosv > 0.f)) phi = cosv;                 // easy_margin
        const float lgp = S_SCALE * phi, lgc = S_SCALE * cosv;
        // main loop summed the target col as a plain class: swap it for phi
        const float tt = tot - __expf(lgc - S_SCALE) + __expf(lgp - S_SCALE);
        nll[m] = (logf(fmaxf(tt, 1e-30f)) + S_SCALE) - lgp;
    }
}

// ---------------- Kernel 3: mean ----------------
__global__ void reduce_mean(const float* __restrict__ nll, float* __restrict__ out) {
    const int t = threadIdx.x; // 512
    float s = nll[t];
#pragma unroll
    for (int d = 1; d < 64; d <<= 1) s += __shfl_xor(s, d);
    __shared__ float red[8];
    if ((t & 63) == 0) red[t >> 6] = s;
    __syncthreads();
    if (t == 0) {
        float tot = 0.f;
#pragma unroll
        for (int i = 0; i < 8; ++i) tot += red[i];
        out[0] = tot / (float)BATCH;
    }
}

extern "C" void kernel_launch(void* const* d_in, const int* in_sizes, int n_in,
                              void* d_out, int out_size, void* d_ws, size_t ws_size,
                              hipStream_t stream) {
    const float* x = (const float*)d_in[0];
    const float* w = (const float*)d_in[1];
    const int* target = (const int*)d_in[2];

    char* ws = (char*)d_ws;
    u16* xn        = (u16*)ws;
    float* partials= (float*)(ws + 524288);
    float* nll     = (float*)(ws + 655360);

    arcface_main<<<GRID, 512, 0, stream>>>(x, w, xn, partials);
    reduce_lse<<<BATCH, 64, 0, stream>>>(partials, w, xn, target, nll);
    reduce_mean<<<1, 512, 0, stream>>>(nll, (float*)d_out);
}

// Round 6
// 514.871 us; speedup vs baseline: 1.4548x; 1.4125x over previous
//
#include <hip/hip_runtime.h>
#include <hip/hip_bf16.h>
#include <math.h>

#define BATCH 512
#define DIM 512
#define NCLASS 100000
#define BNB 256                      /* block tile cols */
#define NT 391                       /* ceil(100000/256) */
#define NSTREAM 64
#define GRID 256                     /* 4 M-groups x 64 streams = 1 block/CU */
#define S_SCALE 30.0f
#define COSM 0.8775825618903728f
#define SINM 0.4794255386042030f
#define LOG2E 1.44269504088896f

typedef unsigned short u16;
typedef __attribute__((ext_vector_type(8))) short short8;
typedef __attribute__((ext_vector_type(4))) float floatx4;
typedef __attribute__((ext_vector_type(16))) float floatx16;

// ws layout (bytes):
//   [0, 524288)            xn bf16 [512][512]       (published by stream-0 blocks)
//   [524288, 655360)       partials [64][512] f32
//   [655360, 657408)       nll float[512]
//   [657408, +102400000)   wn bf16 [100000][512]    (normalized W, bf16)

__device__ __forceinline__ u16 f2bf(float f) {
    union { __hip_bfloat16 h; u16 u; } c;
    c.h = __float2bfloat16(f);       // RNE, native v_cvt on gfx950
    return c.u;
}
__device__ __forceinline__ float bf2f(u16 b) {
    union { float f; unsigned int u; } v;
    v.u = ((unsigned int)b) << 16;
    return v.f;
}

// ---------------- Kernel 0: normalize W rows -> bf16 wn ----------------
// 12500 blocks x 512 thr = 8 rows/block, 1 wave per row. Pure streaming:
// 205 MB read + 102 MB write.
__global__ void wnorm_kernel(const float* __restrict__ w, u16* __restrict__ wn) {
    const int row = blockIdx.x * 8 + (threadIdx.x >> 6);
    const int t = threadIdx.x & 63;
    const floatx4* wr = (const floatx4*)(w + (size_t)row * DIM);
    floatx4 a = wr[t];
    floatx4 b = wr[t + 64];
    float ss = a[0]*a[0] + a[1]*a[1] + a[2]*a[2] + a[3]*a[3]
             + b[0]*b[0] + b[1]*b[1] + b[2]*b[2] + b[3]*b[3];
#pragma unroll
    for (int d = 1; d < 64; d <<= 1) ss += __shfl_xor(ss, d);
    const float rn = 1.0f / fmaxf(sqrtf(ss), 1e-12f);
    ushort4 ua, ub;
    ua.x = f2bf(a[0]*rn); ua.y = f2bf(a[1]*rn); ua.z = f2bf(a[2]*rn); ua.w = f2bf(a[3]*rn);
    ub.x = f2bf(b[0]*rn); ub.y = f2bf(b[1]*rn); ub.z = f2bf(b[2]*rn); ub.w = f2bf(b[3]*rn);
    u16* orow = wn + (size_t)row * DIM;
    *(ushort4*)(orow + 4*t)       = ua;
    *(ushort4*)(orow + 256 + 4*t) = ub;
}

// ---------------- Kernel 1: A-stationary GEMM over bf16 wn ----------------
// 256 blocks = 4 M-groups (128 rows) x 64 streams; 1 block/CU, 8 waves.
// A (normalized bf16, XOR-swizzled) pinned in LDS [r5-verified addressing].
// B: 16B frags read straight from wn (L3/L2 resident) via a 4-slot named
// register pipeline. Running exp-sums accumulate in LDS pacc (wave-private),
// NOT registers -> VALU-live set ~70 regs, spill-proof.
// MFMA 32x32x16: A row=lane&31, k=(lane>>5)*8+j; C/D col=lane&31,
// row=(reg&3)+8*(reg>>2)+4*(lane>>5)   [m74/m101-verified; r3-r5 correct].
__global__ __launch_bounds__(512, 2) void arcface_main(
        const float* __restrict__ x, const u16* __restrict__ wn,
        u16* __restrict__ xn, float* __restrict__ partials) {
    __shared__ __align__(16) u16 ash[128 * DIM];   // 128 KB swizzled normalized-A
    __shared__ float pacc[8][64];                  // 2 KB running exp-sums

    const int t = threadIdx.x;
    const int bid = blockIdx.x;
    const int stream = bid & 63;
    const int mgrp = bid >> 6;       // 0..3
    const int wv = t >> 6;
    const int lane = t & 63;
    const int l31 = lane & 31;
    const int hi = lane >> 5;
    const int swz = l31 & 7;
    const int g  = wv >> 2;          // m-group within block (64 rows)
    const int np = wv & 3;           // n-slot (64 classes)

    // ---- prologue: normalize 128 x-rows -> bf16 swizzled LDS (r5-verified) ----
    for (int rp = 0; rp < 2; ++rp) {
        const int r = rp * 64 + (t >> 3);
        const int q = t & 7;
        const float* xr = x + (size_t)(mgrp * 128 + r) * DIM;
        floatx4 v[16];
        float ss = 0.f;
#pragma unroll
        for (int i = 0; i < 16; ++i) {
            v[i] = *(const floatx4*)(xr + ((q + (i << 3)) << 2));
            ss += v[i][0]*v[i][0] + v[i][1]*v[i][1] + v[i][2]*v[i][2] + v[i][3]*v[i][3];
        }
        ss += __shfl_xor(ss, 1);
        ss += __shfl_xor(ss, 2);
        ss += __shfl_xor(ss, 4);
        const float rn = 1.0f / fmaxf(sqrtf(ss), 1e-12f);
#pragma unroll
        for (int i = 0; i < 16; ++i) {
            const int col4 = q + (i << 3);
            const int gp = (col4 >> 1) ^ (r & 7);
            ushort4 u;
            u.x = f2bf(v[i][0]*rn); u.y = f2bf(v[i][1]*rn);
            u.z = f2bf(v[i][2]*rn); u.w = f2bf(v[i][3]*rn);
            *(ushort4*)(&ash[r * DIM + gp * 8 + (col4 & 1) * 4]) = u;
            if (stream == 0)   // publish exact bf16 x-hat for reduce_lse
                *(ushort4*)(xn + (size_t)(mgrp * 128 + r) * DIM + col4 * 4) = u;
        }
    }
    ((float*)pacc)[t < 512 ? t : 0] = 0.f;   // t always < 512: zero 8x64
    __syncthreads();

    const int arow0 = (g * 64 + l31) * DIM;        // mf=0 rows
    const int arow1 = (g * 64 + 32 + l31) * DIM;   // mf=1 rows
    const float sa = S_SCALE * LOG2E;
    const float sb = -S_SCALE * LOG2E;

    for (int tile = stream; tile < NT; tile += NSTREAM) {
        const int cb0 = tile * BNB + np * 64;
        const int cb1 = cb0 + 32;
        const bool vf0 = cb0 < NCLASS;   // NCLASS%32==0: frags never partial
        const bool vf1 = cb1 < NCLASS;
        const u16* wp0 = wn + (size_t)min(cb0 + l31, NCLASS - 1) * DIM + hi * 8;
        const u16* wp1 = wn + (size_t)min(cb1 + l31, NCLASS - 1) * DIM + hi * 8;

        floatx16 acc00 = (floatx16)0.0f, acc01 = (floatx16)0.0f;
        floatx16 acc10 = (floatx16)0.0f, acc11 = (floatx16)0.0f;

        // 4-slot named B pipeline (distance 4 ks ~ 280 cy of L2-latency cover)
        short8 s0a = *(const short8*)(wp0 +  0), s0b = *(const short8*)(wp1 +  0);
        short8 s1a = *(const short8*)(wp0 + 16), s1b = *(const short8*)(wp1 + 16);
        short8 s2a = *(const short8*)(wp0 + 32), s2b = *(const short8*)(wp1 + 32);
        short8 s3a = *(const short8*)(wp0 + 48), s3b = *(const short8*)(wp1 + 48);

#pragma unroll
        for (int ks = 0; ks < 32; ks += 4) {
#define STEP(K, BA, BB)                                                          \
            {                                                                    \
                const int gb = ((((K) << 1) + hi) ^ swz) << 3;                   \
                const short8 a0 = *(const short8*)(&ash[arow0 + gb]);            \
                const short8 a1 = *(const short8*)(&ash[arow1 + gb]);            \
                acc00 = __builtin_amdgcn_mfma_f32_32x32x16_bf16(a0, BA, acc00, 0, 0, 0); \
                acc10 = __builtin_amdgcn_mfma_f32_32x32x16_bf16(a1, BA, acc10, 0, 0, 0); \
                acc01 = __builtin_amdgcn_mfma_f32_32x32x16_bf16(a0, BB, acc01, 0, 0, 0); \
                acc11 = __builtin_amdgcn_mfma_f32_32x32x16_bf16(a1, BB, acc11, 0, 0, 0); \
                if ((K) + 4 < 32) {                                              \
                    BA = *(const short8*)(wp0 + ((K) + 4) * 16);                 \
                    BB = *(const short8*)(wp1 + ((K) + 4) * 16);                 \
                }                                                                \
            }
            STEP(ks + 0, s0a, s0b)
            STEP(ks + 1, s1a, s1b)
            STEP(ks + 2, s2a, s2b)
            STEP(ks + 3, s3a, s3b)
#undef STEP
        }

        // ---- epilogue: exp accumulate into LDS running sums (wave-private) ----
        if (vf0 | vf1) {
#pragma unroll
            for (int r = 0; r < 16; ++r) {
                float p0 = vf0 ? exp2f(fmaf(acc00[r], sa, sb)) : 0.f;
                if (vf1) p0 += exp2f(fmaf(acc01[r], sa, sb));
                float p1 = vf0 ? exp2f(fmaf(acc10[r], sa, sb)) : 0.f;
                if (vf1) p1 += exp2f(fmaf(acc11[r], sa, sb));
                p0 += __shfl_xor(p0, 1);  p1 += __shfl_xor(p1, 1);
                p0 += __shfl_xor(p0, 2);  p1 += __shfl_xor(p1, 2);
                p0 += __shfl_xor(p0, 4);  p1 += __shfl_xor(p1, 4);
                p0 += __shfl_xor(p0, 8);  p1 += __shfl_xor(p1, 8);
                p0 += __shfl_xor(p0, 16); p1 += __shfl_xor(p1, 16);
                if (l31 == 0) {
                    const int row32 = (r & 3) + ((r >> 2) << 3) + (hi << 2);
                    pacc[wv][row32]      += p0;
                    pacc[wv][32 + row32] += p1;
                }
            }
        }
    }

    __syncthreads();
    if (t < 128) {
        const int g2 = t >> 6, i64 = t & 63;
        const float s = pacc[g2*4+0][i64] + pacc[g2*4+1][i64]
                      + pacc[g2*4+2][i64] + pacc[g2*4+3][i64];
        partials[(size_t)stream * BATCH + mgrp * 128 + t] = s;
    }
}

// ---------------- Kernel 2: LSE + exact target term + nll ----------------
__global__ void reduce_lse(const float* __restrict__ partials,
                           const u16* __restrict__ wn,
                           const u16* __restrict__ xn,
                           const int* __restrict__ target,
                           float* __restrict__ nll) {
    const int m = blockIdx.x;
    const int t = threadIdx.x; // 64 = 1 wave
    float tot = partials[(size_t)t * BATCH + m];
#pragma unroll
    for (int d = 1; d < 64; d <<= 1) tot += __shfl_xor(tot, d);

    const int tg = target[m];
    const short8 wv8 = *(const short8*)(wn + (size_t)tg * DIM + t * 8);
    const short8 xv  = *(const short8*)(xn + (size_t)m  * DIM + t * 8);
    float dot = 0.f;
#pragma unroll
    for (int j = 0; j < 8; ++j)
        dot += bf2f((u16)xv[j]) * bf2f((u16)wv8[j]);
#pragma unroll
    for (int d = 1; d < 64; d <<= 1) dot += __shfl_xor(dot, d);

    if (t == 0) {
        const float cosv = dot;                          // both unit bf16 vectors
        const float sine = sqrtf(fmaxf(1.f - cosv * cosv, 0.f));
        float phi = cosv * COSM - sine * SINM;
        if (!(cosv > 0.f)) phi = cosv;                   // easy_margin
        const float lgp = S_SCALE * phi, lgc = S_SCALE * cosv;
        // main loop summed the target col as a plain class: swap it for phi
        const float tt = tot - __expf(lgc - S_SCALE) + __expf(lgp - S_SCALE);
        nll[m] = (logf(fmaxf(tt, 1e-30f)) + S_SCALE) - lgp;
    }
}

// ---------------- Kernel 3: mean ----------------
__global__ void reduce_mean(const float* __restrict__ nll, float* __restrict__ out) {
    const int t = threadIdx.x; // 512
    float s = nll[t];
#pragma unroll
    for (int d = 1; d < 64; d <<= 1) s += __shfl_xor(s, d);
    __shared__ float red[8];
    if ((t & 63) == 0) red[t >> 6] = s;
    __syncthreads();
    if (t == 0) {
        float tot = 0.f;
#pragma unroll
        for (int i = 0; i < 8; ++i) tot += red[i];
        out[0] = tot / (float)BATCH;
    }
}

extern "C" void kernel_launch(void* const* d_in, const int* in_sizes, int n_in,
                              void* d_out, int out_size, void* d_ws, size_t ws_size,
                              hipStream_t stream) {
    const float* x = (const float*)d_in[0];
    const float* w = (const float*)d_in[1];
    const int* target = (const int*)d_in[2];

    char* ws = (char*)d_ws;
    u16* xn        = (u16*)ws;
    float* partials= (float*)(ws + 524288);
    float* nll     = (float*)(ws + 655360);
    u16* wn        = (u16*)(ws + 657408);   // 102.4 MB

    wnorm_kernel<<<12500, 512, 0, stream>>>(w, wn);
    arcface_main<<<GRID, 512, 0, stream>>>(x, wn, xn, partials);
    reduce_lse<<<BATCH, 64, 0, stream>>>(partials, wn, xn, target, nll);
    reduce_mean<<<1, 512, 0, stream>>>(nll, (float*)d_out);
}